// Round 1
// baseline (615.132 us; speedup 1.0000x reference)
//
#include <hip/hip_runtime.h>

// Problem constants (match reference)
#define NROWS_PER_BLK 64
#define NTHREADS      512
#define DEEP_IN       164     // 64 user + 64 item + 32 cat + 2 price + 2 temporal
#define H1            128
#define H2            64
#define H3            32
#define DIM2_C        10000
#define BN_RS         0.99999500003749968750f  // rsqrt(1 + 1e-5), but compute at runtime anyway

// LDS arena layout (floats):
//   xs   : [0, 10496)   64 x 164 row-major          (phase 0 .. layer-1 compute)
//   h1s  : [0, 8192)    64 x 128 chunk-swizzled     (after barrier; xs dead)
//   h2s  : [8192,12288) 64 x 64  chunk-swizzled
//   h3s  : [12288,14336)64 x 32  chunk-swizzled
//   wide : [14336,14400)
#define ARENA_F 14400

__global__ __launch_bounds__(NTHREADS) void wad_fused(
    const float* __restrict__ user, const float* __restrict__ price,
    const float* __restrict__ temporal, const float* __restrict__ item_emb,
    const float* __restrict__ cat_emb, const float* __restrict__ we1,
    const float* __restrict__ we2, const float* __restrict__ crossW,
    const int* __restrict__ item_ids, const int* __restrict__ cat_ids,
    const int* __restrict__ wf1, const int* __restrict__ wf2,
    const float* __restrict__ W1, const float* __restrict__ b1,
    const float* __restrict__ W2, const float* __restrict__ b2,
    const float* __restrict__ W3, const float* __restrict__ b3,
    const float* __restrict__ W4, const float* __restrict__ b4,
    const float* __restrict__ g1, const float* __restrict__ be1,
    const float* __restrict__ g2, const float* __restrict__ be2,
    const float* __restrict__ g3, const float* __restrict__ be3,
    float* __restrict__ out)
{
    __shared__ float arena[ARENA_F];
    float* xs    = arena;
    float* h1s   = arena;          // reused after barrier
    float* h2s   = arena + 8192;
    float* h3s   = arena + 12288;
    float* wideS = arena + 14336;

    const int tid  = threadIdx.x;
    const int lane = tid & 63;
    const int wave = tid >> 6;
    const int r0   = blockIdx.x * NROWS_PER_BLK;

    const float bn_rs = rsqrtf(1.0f + 1e-5f);

    // ---------------- phase 0: gather X tile + wide term ----------------
    for (int idx = tid; idx < NROWS_PER_BLK * DEEP_IN; idx += NTHREADS) {
        int r = idx / DEEP_IN;
        int k = idx - r * DEEP_IN;
        int R = r0 + r;
        float v;
        if (k < 64)       v = user[R * 64 + k];
        else if (k < 128) v = item_emb[item_ids[R] * 64 + (k - 64)];
        else if (k < 160) v = cat_emb[cat_ids[R] * 32 + (k - 128)];
        else if (k < 162) v = price[R * 2 + (k - 160)];
        else              v = temporal[R * 2 + (k - 162)];
        xs[idx] = v;
    }
    if (tid < NROWS_PER_BLK) {
        int R = r0 + tid;
        int f1 = wf1[R], f2 = wf2[R];
        wideS[tid] = we1[f1] + we2[f2] + crossW[f1 * DIM2_C + f2];
    }
    __syncthreads();

    // ---------------- layer 1: [164] -> [128], lane=row, wave owns 16 cols ----------------
    const int c0 = __builtin_amdgcn_readfirstlane(wave * 16);
    float acc[16];
#pragma unroll
    for (int n = 0; n < 16; ++n) acc[n] = 0.0f;
    {
        const float* xrow = xs + lane * DEEP_IN;
        for (int kq = 0; kq < DEEP_IN / 4; ++kq) {
            float4 a = *(const float4*)(xrow + kq * 4);
            const float* wbase = W1 + kq * 4 * H1 + c0;   // wave-uniform address
#pragma unroll
            for (int kk = 0; kk < 4; ++kk) {
                float av = ((const float*)&a)[kk];
#pragma unroll
                for (int n = 0; n < 16; ++n) acc[n] += av * wbase[kk * H1 + n];
            }
        }
    }
    __syncthreads();   // all xs reads complete before h1s overwrites the region

    // epilogue: bias + eval-BN + relu, store swizzled h1s
#pragma unroll
    for (int n = 0; n < 16; n += 4) {
        float4 o;
#pragma unroll
        for (int e = 0; e < 4; ++e) {
            int c = c0 + n + e;
            float z = (acc[n + e] + b1[c]) * (g1[c] * bn_rs) + be1[c];
            ((float*)&o)[e] = fmaxf(z, 0.0f);
        }
        int kc  = (c0 + n) >> 2;            // chunk 0..31
        int kcs = kc ^ (lane & 7);          // XOR swizzle -> conflict-free b128
        *(float4*)(h1s + lane * H1 + kcs * 4) = o;
    }
    __syncthreads();

    // ---------------- layer 2: [128] -> [64], wave owns 8 cols ----------------
    const int c02 = __builtin_amdgcn_readfirstlane(wave * 8);
    float acc2[8];
#pragma unroll
    for (int n = 0; n < 8; ++n) acc2[n] = 0.0f;
    for (int kq = 0; kq < H1 / 4; ++kq) {
        int kcs = kq ^ (lane & 7);
        float4 a = *(const float4*)(h1s + lane * H1 + kcs * 4);
        const float* wbase = W2 + kq * 4 * H2 + c02;
#pragma unroll
        for (int kk = 0; kk < 4; ++kk) {
            float av = ((const float*)&a)[kk];
#pragma unroll
            for (int n = 0; n < 8; ++n) acc2[n] += av * wbase[kk * H2 + n];
        }
    }
#pragma unroll
    for (int n = 0; n < 8; n += 4) {
        float4 o;
#pragma unroll
        for (int e = 0; e < 4; ++e) {
            int c = c02 + n + e;
            float z = (acc2[n + e] + b2[c]) * (g2[c] * bn_rs) + be2[c];
            ((float*)&o)[e] = fmaxf(z, 0.0f);
        }
        int kc  = (c02 + n) >> 2;           // chunk 0..15
        int kcs = kc ^ (lane & 7);
        *(float4*)(h2s + lane * H2 + kcs * 4) = o;
    }
    __syncthreads();

    // ---------------- layer 3: [64] -> [32], wave owns 4 cols ----------------
    const int c03 = __builtin_amdgcn_readfirstlane(wave * 4);
    float acc3[4];
#pragma unroll
    for (int n = 0; n < 4; ++n) acc3[n] = 0.0f;
    for (int kq = 0; kq < H2 / 4; ++kq) {
        int kcs = kq ^ (lane & 7);
        float4 a = *(const float4*)(h2s + lane * H2 + kcs * 4);
        const float* wbase = W3 + kq * 4 * H3 + c03;
#pragma unroll
        for (int kk = 0; kk < 4; ++kk) {
            float av = ((const float*)&a)[kk];
#pragma unroll
            for (int n = 0; n < 4; ++n) acc3[n] += av * wbase[kk * H3 + n];
        }
    }
    {
        float4 o;
#pragma unroll
        for (int e = 0; e < 4; ++e) {
            int c = c03 + e;
            float z = (acc3[e] + b3[c]) * (g3[c] * bn_rs) + be3[c];
            ((float*)&o)[e] = fmaxf(z, 0.0f);
        }
        int kc  = c03 >> 2;                 // chunk 0..7 (== wave)
        int kcs = kc ^ (lane & 7);
        *(float4*)(h3s + lane * H3 + kcs * 4) = o;
    }
    __syncthreads();

    // ---------------- layer 4 + wide: [32] -> [1] ----------------
    if (tid < NROWS_PER_BLK) {
        int j = tid;
        float s = b4[0];
#pragma unroll
        for (int kq = 0; kq < H3 / 4; ++kq) {
            int kcs = kq ^ (j & 7);
            float4 a = *(const float4*)(h3s + j * H3 + kcs * 4);
#pragma unroll
            for (int e = 0; e < 4; ++e) s += ((const float*)&a)[e] * W4[kq * 4 + e];
        }
        out[r0 + j] = s + wideS[j];
    }
}

extern "C" void kernel_launch(void* const* d_in, const int* in_sizes, int n_in,
                              void* d_out, int out_size, void* d_ws, size_t ws_size,
                              hipStream_t stream) {
    const float* user     = (const float*)d_in[0];
    const float* price    = (const float*)d_in[1];
    const float* temporal = (const float*)d_in[2];
    const float* item_emb = (const float*)d_in[3];
    const float* cat_emb  = (const float*)d_in[4];
    const float* we1      = (const float*)d_in[5];
    const float* we2      = (const float*)d_in[6];
    const float* crossW   = (const float*)d_in[7];
    const int*   item_ids = (const int*)d_in[8];
    const int*   cat_ids  = (const int*)d_in[9];
    const int*   wf1      = (const int*)d_in[10];
    const int*   wf2      = (const int*)d_in[11];
    const float* W1 = (const float*)d_in[12];
    const float* b1 = (const float*)d_in[13];
    const float* W2 = (const float*)d_in[14];
    const float* b2 = (const float*)d_in[15];
    const float* W3 = (const float*)d_in[16];
    const float* b3 = (const float*)d_in[17];
    const float* W4 = (const float*)d_in[18];
    const float* b4 = (const float*)d_in[19];
    const float* g1  = (const float*)d_in[20];
    const float* be1 = (const float*)d_in[21];
    const float* g2  = (const float*)d_in[22];
    const float* be2 = (const float*)d_in[23];
    const float* g3  = (const float*)d_in[24];
    const float* be3 = (const float*)d_in[25];
    float* out = (float*)d_out;

    const int nblocks = 16384 / NROWS_PER_BLK;  // 256
    wad_fused<<<nblocks, NTHREADS, 0, stream>>>(
        user, price, temporal, item_emb, cat_emb, we1, we2, crossW,
        item_ids, cat_ids, wf1, wf2,
        W1, b1, W2, b2, W3, b3, W4, b4,
        g1, be1, g2, be2, g3, be3, out);
}